// Round 1
// baseline (755.696 us; speedup 1.0000x reference)
//
#include <hip/hip_runtime.h>
#include <cstdint>
#include <cmath>

#define T_ 48
#define B_ 16
#define E_ 512
#define V_ 50000
#define S_ 40000
#define G_ 32
#define K_ 8
#define NUMC 20
#define ROWS (T_*B_)      // 768
#define V4 (V_/4)         // 12500
#define E4 (E_/4)         // 128

// ---------------- Kernel A: loc_ctx = location_context + window_sum/num_C ----
__global__ __launch_bounds__(256) void k_locctx(const float4* __restrict__ word,
                                                const float4* __restrict__ prev,
                                                const float4* __restrict__ locc,
                                                float4* __restrict__ out) {
    int f = blockIdx.x * 256 + threadIdx.x;
    if (f >= T_ * B_ * E4) return;
    int e4 = f % E4;
    int tb = f / E4;
    int b = tb % B_;
    int t = tb / B_;
    float4 acc = make_float4(0.f, 0.f, 0.f, 0.f);
    #pragma unroll
    for (int d = 0; d < NUMC; ++d) {
        int src = t - d;
        float4 v;
        if (src >= 0) v = word[(src * B_ + b) * E4 + e4];
        else          v = prev[((T_ + src) * B_ + b) * E4 + e4];
        acc.x += v.x; acc.y += v.y; acc.z += v.z; acc.w += v.w;
    }
    float4 l = locc[f];
    out[f] = make_float4(l.x + acc.x / (float)NUMC,
                         l.y + acc.y / (float)NUMC,
                         l.z + acc.z / (float)NUMC,
                         l.w + acc.w / (float)NUMC);
}

// ---------------- Kernel B: fused per-row top-8 + logsumexp ------------------
__global__ __launch_bounds__(256) void k_topk_lse(const float* __restrict__ logits,
                                                  int* __restrict__ topk,
                                                  float* __restrict__ lse) {
    __shared__ float sv[256][8];
    __shared__ int   si[256][8];
    __shared__ float sm[256];
    __shared__ float ss[256];
    int row = blockIdx.x;
    int tid = threadIdx.x;
    const float4* rp = (const float4*)(logits + (size_t)row * V_);

    float tv[8]; int ti[8];
    #pragma unroll
    for (int i = 0; i < 8; ++i) { tv[i] = -INFINITY; ti[i] = 0x7fffffff; }
    float m = -INFINITY, s = 0.f;

    for (int it = tid; it < V4; it += 256) {
        float4 v = rp[it];
        float xs[4] = {v.x, v.y, v.z, v.w};
        int base = it * 4;
        #pragma unroll
        for (int c = 0; c < 4; ++c) {
            float x = xs[c];
            // online logsumexp
            if (x > m) { s = s * __expf(m - x) + 1.0f; m = x; }
            else       { s += __expf(x - m); }
            // top-8 insertion (scan order is ascending index within thread,
            // so strict > preserves smallest-index-first on ties)
            if (x > tv[7]) {
                int idx = base + c;
                tv[7] = x; ti[7] = idx;
                #pragma unroll
                for (int j = 7; j > 0; --j) {
                    bool sw = (tv[j] > tv[j-1]) || (tv[j] == tv[j-1] && ti[j] < ti[j-1]);
                    if (sw) {
                        float fv = tv[j]; tv[j] = tv[j-1]; tv[j-1] = fv;
                        int   fi = ti[j]; ti[j] = ti[j-1]; ti[j-1] = fi;
                    }
                }
            }
        }
    }

    sm[tid] = m; ss[tid] = s;
    #pragma unroll
    for (int i = 0; i < 8; ++i) { sv[tid][i] = tv[i]; si[tid][i] = ti[i]; }
    __syncthreads();

    for (int stride = 128; stride >= 1; stride >>= 1) {
        if (tid < stride) {
            // logsumexp combine
            float m1 = sm[tid], s1 = ss[tid];
            float m2 = sm[tid + stride], s2 = ss[tid + stride];
            float mm = fmaxf(m1, m2);
            ss[tid] = s1 * __expf(m1 - mm) + s2 * __expf(m2 - mm);
            sm[tid] = mm;
            // top-8 two-pointer merge (desc value, asc index tie-break)
            float ov[8]; int oi[8];
            int pa = 0, pb = 0;
            #pragma unroll
            for (int r = 0; r < 8; ++r) {
                float aval = sv[tid][pa],        bval = sv[tid + stride][pb];
                int   aidx = si[tid][pa],        bidx = si[tid + stride][pb];
                bool ta = (aval > bval) || (aval == bval && aidx < bidx);
                if (ta) { ov[r] = aval; oi[r] = aidx; ++pa; }
                else    { ov[r] = bval; oi[r] = bidx; ++pb; }
            }
            #pragma unroll
            for (int r = 0; r < 8; ++r) { sv[tid][r] = ov[r]; si[tid][r] = oi[r]; }
        }
        __syncthreads();
    }

    if (tid < 8) topk[row * K_ + tid] = si[0][tid];
    if (tid == 0) lse[row] = sm[0] + logf(ss[0]);
}

// ---------------- Kernel C: predictions_globals = logits - lse[row] ----------
__global__ __launch_bounds__(256) void k_logsoftmax(const float4* __restrict__ logits,
                                                    const float* __restrict__ lse,
                                                    float4* __restrict__ out) {
    int row = blockIdx.y;
    int i4 = blockIdx.x * 256 + threadIdx.x;
    if (i4 >= V4) return;
    float l = lse[row];
    size_t o = (size_t)row * V4 + i4;
    float4 v = logits[o];
    out[o] = make_float4(v.x - l, v.y - l, v.z - l, v.w - l);
}

// ---------------- Kernel D: fill predictions_senses with log(eps) ------------
__global__ __launch_bounds__(256) void k_fill(float4* __restrict__ out, float val, int n4) {
    int i = blockIdx.x * 256 + threadIdx.x;
    if (i < n4) out[i] = make_float4(val, val, val, val);
}

// ---------------- Kernel E: cos-sim argmax over 256 gathered senses ----------
__global__ __launch_bounds__(256) void k_sense(const float* __restrict__ loc,
                                               const int* __restrict__ topk,
                                               const int* __restrict__ neigh,
                                               const float* __restrict__ SC,
                                               float* __restrict__ outS,
                                               float log_chosen) {
    __shared__ __align__(16) float a[E_];
    __shared__ int   sidx[K_ * G_];
    __shared__ float warr[4];
    __shared__ float wbv[4];
    __shared__ int   wbn[4];
    __shared__ float a_n;

    int row = blockIdx.x;   // t*B + b
    int tid = threadIdx.x;
    int lane = tid & 63, w = tid >> 6;

    float a0 = loc[(size_t)row * E_ + tid];
    float a1 = loc[(size_t)row * E_ + 256 + tid];
    a[tid] = a0; a[tid + 256] = a1;
    // sense index list in flattened (k*G+g) order == reference reshape order
    sidx[tid] = neigh[(size_t)topk[row * K_ + (tid >> 5)] * G_ + (tid & 31)];

    // ||a|| block reduction
    float p = a0 * a0 + a1 * a1;
    #pragma unroll
    for (int off = 32; off; off >>= 1) p += __shfl_down(p, off);
    if (lane == 0) warr[w] = p;
    __syncthreads();
    if (tid == 0) a_n = fmaxf(sqrtf(warr[0] + warr[1] + warr[2] + warr[3]), 1e-8f);
    __syncthreads();

    const float4* a4 = (const float4*)a;
    float4 aA = a4[lane], aB = a4[lane + 64];

    float best = -INFINITY; int bn = 0x7fffffff;
    for (int n = w; n < K_ * G_; n += 4) {
        const float4* sp = (const float4*)(SC + (size_t)sidx[n] * E_);
        float4 sA = sp[lane], sB = sp[lane + 64];
        float dot = sA.x * aA.x + sA.y * aA.y + sA.z * aA.z + sA.w * aA.w
                  + sB.x * aB.x + sB.y * aB.y + sB.z * aB.z + sB.w * aB.w;
        float nr  = sA.x * sA.x + sA.y * sA.y + sA.z * sA.z + sA.w * sA.w
                  + sB.x * sB.x + sB.y * sB.y + sB.z * sB.z + sB.w * sB.w;
        #pragma unroll
        for (int off = 32; off; off >>= 1) {
            dot += __shfl_down(dot, off);
            nr  += __shfl_down(nr,  off);
        }
        if (lane == 0) {
            float bnorm = fmaxf(sqrtf(nr), 1e-8f);
            float cs = dot / (a_n * bnorm);
            // ascending n within wave: strict > keeps first occurrence
            if (cs > best) { best = cs; bn = n; }
        }
    }
    if (lane == 0) { wbv[w] = best; wbn[w] = bn; }
    __syncthreads();
    if (tid == 0) {
        float bv = wbv[0]; int bnn = wbn[0];
        #pragma unroll
        for (int i = 1; i < 4; ++i) {
            if (wbv[i] > bv || (wbv[i] == bv && wbn[i] < bnn)) { bv = wbv[i]; bnn = wbn[i]; }
        }
        int sense = sidx[bnn];
        outS[(size_t)row * S_ + sense] = log_chosen;
    }
}

// ---------------- launch -----------------------------------------------------
extern "C" void kernel_launch(void* const* d_in, const int* in_sizes, int n_in,
                              void* d_out, int out_size, void* d_ws, size_t ws_size,
                              hipStream_t stream) {
    const float* word   = (const float*)d_in[0];
    const float* prev   = (const float*)d_in[1];
    const float* locc   = (const float*)d_in[2];
    const float* logits = (const float*)d_in[3];
    const float* SC     = (const float*)d_in[4];
    const int*   neigh  = (const int*)d_in[5];
    // d_in[6] = K (8), d_in[7] = num_C (20): compile-time constants here.

    float* out_g = (float*)d_out;                       // ROWS*V_ (log-softmax)
    float* out_s = out_g + (size_t)ROWS * V_;           // ROWS*S_ (senses)

    float* loc  = (float*)d_ws;                         // T_*B_*E_ floats
    int*   topk = (int*)(loc + (size_t)T_ * B_ * E_);   // ROWS*K_ ints
    float* lse  = (float*)(topk + ROWS * K_);           // ROWS floats

    k_locctx<<<dim3((T_ * B_ * E4 + 255) / 256), 256, 0, stream>>>(
        (const float4*)word, (const float4*)prev, (const float4*)locc, (float4*)loc);

    k_topk_lse<<<ROWS, 256, 0, stream>>>(logits, topk, lse);

    k_logsoftmax<<<dim3((V4 + 255) / 256, ROWS), 256, 0, stream>>>(
        (const float4*)logits, lse, (float4*)out_g);

    float fillv = logf(1e-8f);
    k_fill<<<(ROWS * (S_ / 4) + 255) / 256, 256, 0, stream>>>(
        (float4*)out_s, fillv, ROWS * (S_ / 4));

    float log_chosen = logf(1.0f - 1e-8f * (float)(S_ - 1));
    k_sense<<<ROWS, 256, 0, stream>>>(loc, topk, neigh, SC, out_s, log_chosen);
}

// Round 2
// 542.773 us; speedup vs baseline: 1.3923x; 1.3923x over previous
//
#include <hip/hip_runtime.h>
#include <cstdint>
#include <cmath>

#define T_ 48
#define B_ 16
#define E_ 512
#define V_ 50000
#define S_ 40000
#define G_ 32
#define K_ 8
#define NUMC 20
#define ROWS (T_*B_)      // 768
#define V4 (V_/4)         // 12500
#define E4 (E_/4)         // 128
#define NCAND 1024

// ---------------- Kernel A: loc_ctx = location_context + window_sum/num_C ----
__global__ __launch_bounds__(256) void k_locctx(const float4* __restrict__ word,
                                                const float4* __restrict__ prev,
                                                const float4* __restrict__ locc,
                                                float4* __restrict__ out) {
    int f = blockIdx.x * 256 + threadIdx.x;
    if (f >= T_ * B_ * E4) return;
    int e4 = f % E4;
    int tb = f / E4;
    int b = tb % B_;
    int t = tb / B_;
    float4 acc = make_float4(0.f, 0.f, 0.f, 0.f);
    #pragma unroll
    for (int d = 0; d < NUMC; ++d) {
        int src = t - d;
        float4 v;
        if (src >= 0) v = word[(src * B_ + b) * E4 + e4];
        else          v = prev[((T_ + src) * B_ + b) * E4 + e4];
        acc.x += v.x; acc.y += v.y; acc.z += v.z; acc.w += v.w;
    }
    float4 l = locc[f];
    out[f] = make_float4(l.x + acc.x / (float)NUMC,
                         l.y + acc.y / (float)NUMC,
                         l.z + acc.z / (float)NUMC,
                         l.w + acc.w / (float)NUMC);
}

// ---------------- Kernel B: per-row top-8 + logsumexp, threshold-select ------
// Pass 1: per-thread max (branch-free stream). tau = 8th largest of the 512
// per-thread maxima => all true top-8 elements >= tau (the 8 threads owning
// the 8 largest maxima each contain a distinct element >= tau).
// Pass 2: branch-free sum of exp2 + rare candidate push; wave 0 extracts the
// exact top-8 from the candidate set with lax.top_k tie-break (index asc).
__global__ __launch_bounds__(512) void k_topk_lse(const float* __restrict__ logits,
                                                  int* __restrict__ topk,
                                                  float* __restrict__ lse) {
    __shared__ float smax[512];
    __shared__ float cand_v[NCAND];
    __shared__ int   cand_i[NCAND];
    __shared__ int   ncand;
    __shared__ float s_m, s_tau;
    __shared__ float ssum[8];

    int row = blockIdx.x;
    int tid = threadIdx.x;
    int lane = tid & 63, w = tid >> 6;
    const float4* rp = (const float4*)(logits + (size_t)row * V_);

    // ---- pass 1: thread max ----
    float m = -INFINITY;
    for (int it = tid; it < V4; it += 512) {
        float4 v = rp[it];
        m = fmaxf(m, fmaxf(fmaxf(v.x, v.y), fmaxf(v.z, v.w)));
    }
    smax[tid] = m;
    if (tid == 0) ncand = 0;
    __syncthreads();

    // ---- wave 0: top-8 of the 512 maxima (values only) ----
    if (tid < 64) {
        float v8[8];
        #pragma unroll
        for (int j = 0; j < 8; ++j) v8[j] = smax[tid * 8 + j];
        #pragma unroll
        for (int r = 0; r < 8; ++r) {
            float lm = v8[0];
            #pragma unroll
            for (int j = 1; j < 8; ++j) lm = fmaxf(lm, v8[j]);
            #pragma unroll
            for (int mask = 1; mask < 64; mask <<= 1)
                lm = fmaxf(lm, __shfl_xor(lm, mask));
            if (tid == 0) {
                if (r == 0) s_m = lm;
                if (r == 7) s_tau = lm;
            }
            // remove all copies (only shrinks tau -> superset of candidates: safe)
            #pragma unroll
            for (int j = 0; j < 8; ++j) if (v8[j] == lm) v8[j] = -INFINITY;
        }
    }
    __syncthreads();

    float rm  = s_m;
    float tau = s_tau;
    const float L2E = 1.4426950408889634f;
    float nml2 = -rm * L2E;

    // ---- pass 2: branch-free exp-sum + rare candidate push ----
    float sum = 0.f;
    for (int it = tid; it < V4; it += 512) {
        float4 v = rp[it];
        float xs[4] = {v.x, v.y, v.z, v.w};
        #pragma unroll
        for (int c = 0; c < 4; ++c) {
            float x = xs[c];
            sum += __builtin_exp2f(__builtin_fmaf(x, L2E, nml2));
            if (x >= tau) {
                int p = atomicAdd(&ncand, 1);
                if (p < NCAND) { cand_v[p] = x; cand_i[p] = it * 4 + c; }
            }
        }
    }
    #pragma unroll
    for (int off = 32; off; off >>= 1) sum += __shfl_down(sum, off);
    if (lane == 0) ssum[w] = sum;
    __syncthreads();

    if (tid == 0) {
        float tot = ssum[0];
        #pragma unroll
        for (int i = 1; i < 8; ++i) tot += ssum[i];
        lse[row] = rm + logf(tot);
    }

    // ---- wave 0: exact top-8 of candidates (value desc, index asc) ----
    if (tid < 64) {
        int C = ncand; if (C > NCAND) C = NCAND;
        for (int r = 0; r < 8; ++r) {
            float bv = -INFINITY; int bi = 0x7fffffff;
            for (int c = tid; c < C; c += 64) {
                float v = cand_v[c]; int i = cand_i[c];
                if (v > bv || (v == bv && i < bi)) { bv = v; bi = i; }
            }
            #pragma unroll
            for (int mask = 1; mask < 64; mask <<= 1) {
                float ov = __shfl_xor(bv, mask);
                int   oi = __shfl_xor(bi, mask);
                if (ov > bv || (ov == bv && oi < bi)) { bv = ov; bi = oi; }
            }
            if (tid == 0) topk[row * K_ + r] = bi;
            for (int c = tid; c < C; c += 64)
                if (cand_i[c] == bi) { cand_v[c] = -INFINITY; cand_i[c] = 0x7fffffff; }
        }
    }
}

// ---------------- Kernel C: predictions_globals = logits - lse[row] ----------
__global__ __launch_bounds__(256) void k_logsoftmax(const float4* __restrict__ logits,
                                                    const float* __restrict__ lse,
                                                    float4* __restrict__ out) {
    int row = blockIdx.y;
    int i4 = blockIdx.x * 256 + threadIdx.x;
    if (i4 >= V4) return;
    float l = lse[row];
    size_t o = (size_t)row * V4 + i4;
    float4 v = logits[o];
    out[o] = make_float4(v.x - l, v.y - l, v.z - l, v.w - l);
}

// ---------------- Kernel D: fill predictions_senses with log(eps) ------------
__global__ __launch_bounds__(256) void k_fill(float4* __restrict__ out, float val, int n4) {
    int i = blockIdx.x * 256 + threadIdx.x;
    if (i < n4) out[i] = make_float4(val, val, val, val);
}

// ---------------- Kernel E: cos-sim argmax over 256 gathered senses ----------
// 512 threads = 8 waves (24 waves/CU), 2 senses in flight per wave iteration.
__global__ __launch_bounds__(512) void k_sense(const float* __restrict__ loc,
                                               const int* __restrict__ topk,
                                               const int* __restrict__ neigh,
                                               const float* __restrict__ SC,
                                               float* __restrict__ outS,
                                               float log_chosen) {
    __shared__ __align__(16) float a[E_];
    __shared__ int   sidx[K_ * G_];
    __shared__ float warr[8];
    __shared__ float wbv[8];
    __shared__ int   wbn[8];
    __shared__ float a_n;

    int row = blockIdx.x;
    int tid = threadIdx.x;
    int lane = tid & 63, w = tid >> 6;

    float a0 = loc[(size_t)row * E_ + tid];
    a[tid] = a0;
    if (tid < K_ * G_)
        sidx[tid] = neigh[(size_t)topk[row * K_ + (tid >> 5)] * G_ + (tid & 31)];

    // ||a|| block reduction
    float p = a0 * a0;
    #pragma unroll
    for (int off = 32; off; off >>= 1) p += __shfl_down(p, off);
    if (lane == 0) warr[w] = p;
    __syncthreads();
    if (tid == 0) {
        float t = warr[0];
        #pragma unroll
        for (int i = 1; i < 8; ++i) t += warr[i];
        a_n = fmaxf(sqrtf(t), 1e-8f);
    }
    __syncthreads();

    const float4* a4 = (const float4*)a;
    float4 aA = a4[lane], aB = a4[lane + 64];
    float an = a_n;

    float best = -INFINITY; int bn = 0x7fffffff;
    for (int n = w; n < K_ * G_; n += 16) {
        int n2 = n + 8;
        const float4* sp0 = (const float4*)(SC + (size_t)sidx[n]  * E_);
        const float4* sp1 = (const float4*)(SC + (size_t)sidx[n2] * E_);
        float4 s0A = sp0[lane], s0B = sp0[lane + 64];
        float4 s1A = sp1[lane], s1B = sp1[lane + 64];
        float dot0 = s0A.x * aA.x + s0A.y * aA.y + s0A.z * aA.z + s0A.w * aA.w
                   + s0B.x * aB.x + s0B.y * aB.y + s0B.z * aB.z + s0B.w * aB.w;
        float nr0  = s0A.x * s0A.x + s0A.y * s0A.y + s0A.z * s0A.z + s0A.w * s0A.w
                   + s0B.x * s0B.x + s0B.y * s0B.y + s0B.z * s0B.z + s0B.w * s0B.w;
        float dot1 = s1A.x * aA.x + s1A.y * aA.y + s1A.z * aA.z + s1A.w * aA.w
                   + s1B.x * aB.x + s1B.y * aB.y + s1B.z * aB.z + s1B.w * aB.w;
        float nr1  = s1A.x * s1A.x + s1A.y * s1A.y + s1A.z * s1A.z + s1A.w * s1A.w
                   + s1B.x * s1B.x + s1B.y * s1B.y + s1B.z * s1B.z + s1B.w * s1B.w;
        #pragma unroll
        for (int off = 32; off; off >>= 1) {
            dot0 += __shfl_down(dot0, off);
            nr0  += __shfl_down(nr0,  off);
            dot1 += __shfl_down(dot1, off);
            nr1  += __shfl_down(nr1,  off);
        }
        if (lane == 0) {
            float cs0 = dot0 / (an * fmaxf(sqrtf(nr0), 1e-8f));
            if (cs0 > best) { best = cs0; bn = n; }
            float cs1 = dot1 / (an * fmaxf(sqrtf(nr1), 1e-8f));
            if (cs1 > best) { best = cs1; bn = n2; }
        }
    }
    if (lane == 0) { wbv[w] = best; wbn[w] = bn; }
    __syncthreads();
    if (tid == 0) {
        float bv = wbv[0]; int bnn = wbn[0];
        #pragma unroll
        for (int i = 1; i < 8; ++i) {
            if (wbv[i] > bv || (wbv[i] == bv && wbn[i] < bnn)) { bv = wbv[i]; bnn = wbn[i]; }
        }
        outS[(size_t)row * S_ + sidx[bnn]] = log_chosen;
    }
}

// ---------------- launch -----------------------------------------------------
extern "C" void kernel_launch(void* const* d_in, const int* in_sizes, int n_in,
                              void* d_out, int out_size, void* d_ws, size_t ws_size,
                              hipStream_t stream) {
    const float* word   = (const float*)d_in[0];
    const float* prev   = (const float*)d_in[1];
    const float* locc   = (const float*)d_in[2];
    const float* logits = (const float*)d_in[3];
    const float* SC     = (const float*)d_in[4];
    const int*   neigh  = (const int*)d_in[5];

    float* out_g = (float*)d_out;                       // ROWS*V_ (log-softmax)
    float* out_s = out_g + (size_t)ROWS * V_;           // ROWS*S_ (senses)

    float* loc  = (float*)d_ws;                         // T_*B_*E_ floats
    int*   topk = (int*)(loc + (size_t)T_ * B_ * E_);   // ROWS*K_ ints
    float* lse  = (float*)(topk + ROWS * K_);           // ROWS floats

    k_locctx<<<dim3((T_ * B_ * E4 + 255) / 256), 256, 0, stream>>>(
        (const float4*)word, (const float4*)prev, (const float4*)locc, (float4*)loc);

    k_topk_lse<<<ROWS, 512, 0, stream>>>(logits, topk, lse);

    k_logsoftmax<<<dim3((V4 + 255) / 256, ROWS), 256, 0, stream>>>(
        (const float4*)logits, lse, (float4*)out_g);

    float fillv = logf(1e-8f);
    k_fill<<<(ROWS * (S_ / 4) + 255) / 256, 256, 0, stream>>>(
        (float4*)out_s, fillv, ROWS * (S_ / 4));

    float log_chosen = logf(1.0f - 1e-8f * (float)(S_ - 1));
    k_sense<<<ROWS, 512, 0, stream>>>(loc, topk, neigh, SC, out_s, log_chosen);
}